// Round 1
// baseline (8812.736 us; speedup 1.0000x reference)
//
#include <hip/hip_runtime.h>
#include <math.h>

// SRNN: S=16 steps, N=32768 nodes, E=131072 spatial edges.
// fp32 baseline. All state lives in d_ws (~136 MB needed).

#define S_LEN 16
#define NN 32768
#define EE 131072

__device__ __forceinline__ float sigmoidf_(float x) {
    return 1.0f / (1.0f + expf(-x));
}

// Generic LSTM step. H = hidden size (input dim == H). Block = 256 threads.
// ENC=1: input is (rows,2), encoded via relu(x @ enc_w(2,H) + enc_b) on the fly.
// ENC=0: input is (rows,H) precomputed.
// Each block: TR rows. Thread (l = t%H, sub = t/H) computes gate columns
// {l, H+l, 2H+l, 3H+l} for 8 rows -> full local c/h update, no reduction.
template<int H, int ENC>
__global__ __launch_bounds__(256) void lstm_step_kernel(
    const float* __restrict__ xin,
    const float* __restrict__ enc_w, const float* __restrict__ enc_b,
    const float* __restrict__ Wih, const float* __restrict__ Whh,
    const float* __restrict__ bias,
    float* __restrict__ h, float* __restrict__ c)
{
    constexpr int SUBS = 256 / H;
    constexpr int RPT  = 8;
    constexpr int TR   = RPT * SUBS;   // 32 rows (H=64), 16 rows (H=128)
    constexpr int G    = 4 * H;
    __shared__ float xls[TR][H];
    __shared__ float hls[TR][H];

    const int row0 = blockIdx.x * TR;
    const int t = threadIdx.x;

    // Stage x (with optional encode) and h into LDS.
    for (int idx = t; idx < TR * H; idx += 256) {
        const int r = idx / H, j = idx % H;
        const int grow = row0 + r;
        float xe;
        if (ENC) {
            const float a0 = xin[grow * 2 + 0];
            const float a1 = xin[grow * 2 + 1];
            xe = fmaxf(0.0f, fmaf(a0, enc_w[j], fmaf(a1, enc_w[H + j], enc_b[j])));
        } else {
            xe = xin[grow * H + j];
        }
        xls[r][j] = xe;
        hls[r][j] = h[grow * H + j];
    }
    __syncthreads();

    const int l   = t % H;   // hidden column
    const int sub = t / H;   // row subset (uniform per wave -> LDS broadcast reads)

    float acc[RPT][4];
    #pragma unroll
    for (int rr = 0; rr < RPT; ++rr) {
        #pragma unroll
        for (int q = 0; q < 4; ++q) acc[rr][q] = bias[q * H + l];
    }

    #pragma unroll 1
    for (int k4 = 0; k4 < H / 4; ++k4) {
        float wih[4][4], whh[4][4];
        #pragma unroll
        for (int j = 0; j < 4; ++j) {
            const int k = k4 * 4 + j;
            #pragma unroll
            for (int q = 0; q < 4; ++q) {
                wih[j][q] = Wih[k * G + q * H + l];
                whh[j][q] = Whh[k * G + q * H + l];
            }
        }
        #pragma unroll
        for (int rr = 0; rr < RPT; ++rr) {
            const int r = sub * RPT + rr;
            const float4 xv = *(reinterpret_cast<const float4*>(&xls[r][0]) + k4);
            const float4 hv = *(reinterpret_cast<const float4*>(&hls[r][0]) + k4);
            #pragma unroll
            for (int q = 0; q < 4; ++q) {
                float a = acc[rr][q];
                a = fmaf(xv.x, wih[0][q], a);
                a = fmaf(xv.y, wih[1][q], a);
                a = fmaf(xv.z, wih[2][q], a);
                a = fmaf(xv.w, wih[3][q], a);
                a = fmaf(hv.x, whh[0][q], a);
                a = fmaf(hv.y, whh[1][q], a);
                a = fmaf(hv.z, whh[2][q], a);
                a = fmaf(hv.w, whh[3][q], a);
                acc[rr][q] = a;
            }
        }
    }

    #pragma unroll
    for (int rr = 0; rr < RPT; ++rr) {
        const int r = sub * RPT + rr;
        const int grow = row0 + r;
        const float ig = sigmoidf_(acc[rr][0]);
        const float fg = sigmoidf_(acc[rr][1]);
        const float gg = tanhf(acc[rr][2]);
        const float og = sigmoidf_(acc[rr][3]);
        const float cold = c[grow * H + l];
        const float c2 = fmaf(fg, cold, ig * gg);
        const float h2 = og * tanhf(c2);
        c[grow * H + l] = c2;
        h[grow * H + l] = h2;
    }
}

// agg[n] += hs[slot/2] for each slot with inc[slot]==n. One float4 per thread.
__global__ __launch_bounds__(256) void scatter_kernel(
    const float* __restrict__ hs, const int* __restrict__ inc,
    float* __restrict__ agg)
{
    const int tid  = blockIdx.x * 256 + threadIdx.x;   // over 2E*16 exactly
    const int slot = tid >> 4;
    const int j4   = tid & 15;
    const int e = slot >> 1;
    const int n = inc[slot];
    const float4 v = *reinterpret_cast<const float4*>(&hs[e * 64 + j4 * 4]);
    float* dst = &agg[n * 64 + j4 * 4];
    atomicAdd(dst + 0, v.x);
    atomicAdd(dst + 1, v.y);
    atomicAdd(dst + 2, v.z);
    atomicAdd(dst + 3, v.w);
}

// x_node[:,0:64] = relu(xn * n_enc_w + n_enc_b)
// x_node[:,64:128] = relu([ht|agg] @ ee_w + ee_b)
__global__ __launch_bounds__(256) void embed_kernel(
    const float* __restrict__ xn, const float* __restrict__ ht,
    const float* __restrict__ agg,
    const float* __restrict__ n_enc_w, const float* __restrict__ n_enc_b,
    const float* __restrict__ ee_w, const float* __restrict__ ee_b,
    float* __restrict__ xnode)
{
    __shared__ float hls[16][64];
    __shared__ float als[16][64];
    const int row0 = blockIdx.x * 16;
    const int t = threadIdx.x;
    for (int idx = t; idx < 16 * 64; idx += 256) {
        const int r = idx >> 6, j = idx & 63;
        hls[r][j] = ht[(row0 + r) * 64 + j];
        als[r][j] = agg[(row0 + r) * 64 + j];
    }
    __syncthreads();

    const int j   = t & 63;
    const int sub = t >> 6;
    float acc[4];
    #pragma unroll
    for (int rr = 0; rr < 4; ++rr) acc[rr] = ee_b[j];

    #pragma unroll 1
    for (int k4 = 0; k4 < 16; ++k4) {
        const float w0 = ee_w[(k4 * 4 + 0) * 64 + j];
        const float w1 = ee_w[(k4 * 4 + 1) * 64 + j];
        const float w2 = ee_w[(k4 * 4 + 2) * 64 + j];
        const float w3 = ee_w[(k4 * 4 + 3) * 64 + j];
        #pragma unroll
        for (int rr = 0; rr < 4; ++rr) {
            const float4 hv = *(reinterpret_cast<const float4*>(&hls[sub * 4 + rr][0]) + k4);
            acc[rr] = fmaf(hv.x, w0, acc[rr]);
            acc[rr] = fmaf(hv.y, w1, acc[rr]);
            acc[rr] = fmaf(hv.z, w2, acc[rr]);
            acc[rr] = fmaf(hv.w, w3, acc[rr]);
        }
    }
    #pragma unroll 1
    for (int k4 = 0; k4 < 16; ++k4) {
        const float w0 = ee_w[(64 + k4 * 4 + 0) * 64 + j];
        const float w1 = ee_w[(64 + k4 * 4 + 1) * 64 + j];
        const float w2 = ee_w[(64 + k4 * 4 + 2) * 64 + j];
        const float w3 = ee_w[(64 + k4 * 4 + 3) * 64 + j];
        #pragma unroll
        for (int rr = 0; rr < 4; ++rr) {
            const float4 av = *(reinterpret_cast<const float4*>(&als[sub * 4 + rr][0]) + k4);
            acc[rr] = fmaf(av.x, w0, acc[rr]);
            acc[rr] = fmaf(av.y, w1, acc[rr]);
            acc[rr] = fmaf(av.z, w2, acc[rr]);
            acc[rr] = fmaf(av.w, w3, acc[rr]);
        }
    }

    #pragma unroll
    for (int rr = 0; rr < 4; ++rr) {
        const int grow = row0 + sub * 4 + rr;
        const float emb = fmaxf(0.0f, acc[rr]);
        const float enc = fmaxf(0.0f, fmaf(xn[grow], n_enc_w[j], n_enc_b[j]));
        xnode[grow * 128 + j]      = enc;
        xnode[grow * 128 + 64 + j] = emb;
    }
}

// out[r] = dot(hn[r,0:128], out_w) + out_b. 4 rows/block, wave per row.
__global__ __launch_bounds__(256) void out_kernel(
    const float* __restrict__ hn, const float* __restrict__ out_w,
    const float* __restrict__ out_b, float* __restrict__ out)
{
    const int r = blockIdx.x * 4 + (threadIdx.x >> 6);
    const int l = threadIdx.x & 63;
    float p = fmaf(hn[r * 128 + l], out_w[l],
                   hn[r * 128 + 64 + l] * out_w[64 + l]);
    #pragma unroll
    for (int off = 32; off > 0; off >>= 1) p += __shfl_down(p, off);
    if (l == 0) out[r] = p + out_b[0];
}

extern "C" void kernel_launch(void* const* d_in, const int* in_sizes, int n_in,
                              void* d_out, int out_size, void* d_ws, size_t ws_size,
                              hipStream_t stream) {
    const float* data_nodes = (const float*)d_in[0];
    const float* data_tE    = (const float*)d_in[1];
    const float* data_sE    = (const float*)d_in[2];
    const float* h_n0 = (const float*)d_in[3];
    const float* c_n0 = (const float*)d_in[4];
    const float* h_t0 = (const float*)d_in[5];
    const float* c_t0 = (const float*)d_in[6];
    const float* h_s0 = (const float*)d_in[7];
    const float* c_s0 = (const float*)d_in[8];
    const int*   inc  = (const int*)d_in[9];
    const float* t_enc_w = (const float*)d_in[10];
    const float* t_enc_b = (const float*)d_in[11];
    const float* t_Wih   = (const float*)d_in[12];
    const float* t_Whh   = (const float*)d_in[13];
    const float* t_b     = (const float*)d_in[14];
    const float* s_enc_w = (const float*)d_in[15];
    const float* s_enc_b = (const float*)d_in[16];
    const float* s_Wih   = (const float*)d_in[17];
    const float* s_Whh   = (const float*)d_in[18];
    const float* s_b     = (const float*)d_in[19];
    const float* n_enc_w = (const float*)d_in[20];
    const float* n_enc_b = (const float*)d_in[21];
    const float* ee_w    = (const float*)d_in[22];
    const float* ee_b    = (const float*)d_in[23];
    const float* n_Wih   = (const float*)d_in[24];
    const float* n_Whh   = (const float*)d_in[25];
    const float* n_b     = (const float*)d_in[26];
    const float* out_w   = (const float*)d_in[27];
    const float* out_b   = (const float*)d_in[28];
    float* out = (float*)d_out;

    // Workspace layout (fp32): needs 35,651,584 floats = ~136 MB.
    float* p = (float*)d_ws;
    float* ht    = p; p += (size_t)NN * 64;
    float* ct    = p; p += (size_t)NN * 64;
    float* hs    = p; p += (size_t)EE * 64;
    float* cs    = p; p += (size_t)EE * 64;
    float* hn    = p; p += (size_t)NN * 128;
    float* cn    = p; p += (size_t)NN * 128;
    float* agg   = p; p += (size_t)NN * 64;
    float* xnode = p; p += (size_t)NN * 128;

    // Initialize recurrent state from inputs (inputs never mutated).
    hipMemcpyAsync(ht, h_t0, (size_t)NN * 64 * 4, hipMemcpyDeviceToDevice, stream);
    hipMemcpyAsync(ct, c_t0, (size_t)NN * 64 * 4, hipMemcpyDeviceToDevice, stream);
    hipMemcpyAsync(hs, h_s0, (size_t)EE * 64 * 4, hipMemcpyDeviceToDevice, stream);
    hipMemcpyAsync(cs, c_s0, (size_t)EE * 64 * 4, hipMemcpyDeviceToDevice, stream);
    hipMemcpyAsync(hn, h_n0, (size_t)NN * 128 * 4, hipMemcpyDeviceToDevice, stream);
    hipMemcpyAsync(cn, c_n0, (size_t)NN * 128 * 4, hipMemcpyDeviceToDevice, stream);

    for (int st = 0; st < S_LEN; ++st) {
        const float* xt = data_tE + (size_t)st * NN * 2;
        const float* xs = data_sE + (size_t)st * EE * 2;
        const float* xn = data_nodes + (size_t)st * NN;

        // temporal edge LSTM (H=64, fused encoder)
        lstm_step_kernel<64, 1><<<NN / 32, 256, 0, stream>>>(
            xt, t_enc_w, t_enc_b, t_Wih, t_Whh, t_b, ht, ct);
        // spatial edge LSTM (H=64, fused encoder)
        lstm_step_kernel<64, 1><<<EE / 32, 256, 0, stream>>>(
            xs, s_enc_w, s_enc_b, s_Wih, s_Whh, s_b, hs, cs);
        // aggregate spatial hidden states into nodes
        hipMemsetAsync(agg, 0, (size_t)NN * 64 * 4, stream);
        scatter_kernel<<<(2 * EE * 16) / 256, 256, 0, stream>>>(hs, inc, agg);
        // node LSTM input: [enc | relu([ht|agg] @ ee_w + ee_b)]
        embed_kernel<<<NN / 16, 256, 0, stream>>>(
            xn, ht, agg, n_enc_w, n_enc_b, ee_w, ee_b, xnode);
        // node LSTM (H=128, input precomputed)
        lstm_step_kernel<128, 0><<<NN / 16, 256, 0, stream>>>(
            xnode, nullptr, nullptr, n_Wih, n_Whh, n_b, hn, cn);
        // output projection
        out_kernel<<<NN / 4, 256, 0, stream>>>(hn, out_w, out_b, out + (size_t)st * NN);
    }
}

// Round 2
// 5692.234 us; speedup vs baseline: 1.5482x; 1.5482x over previous
//
#include <hip/hip_runtime.h>
#include <math.h>

// SRNN: S=16 steps, N=32768 nodes, E=131072 spatial edges.
// fp32 baseline + CSR gather for edge->node aggregation.
// Workspace: ~139 MB needed.

#define S_LEN 16
#define NN 32768
#define EE 131072

__device__ __forceinline__ float sigmoidf_(float x) {
    return 1.0f / (1.0f + expf(-x));
}

// Generic LSTM step. H = hidden size (input dim == H). Block = 256 threads.
// ENC=1: input is (rows,2), encoded via relu(x @ enc_w(2,H) + enc_b) on the fly.
// ENC=0: input is (rows,H) precomputed.
template<int H, int ENC>
__global__ __launch_bounds__(256) void lstm_step_kernel(
    const float* __restrict__ xin,
    const float* __restrict__ enc_w, const float* __restrict__ enc_b,
    const float* __restrict__ Wih, const float* __restrict__ Whh,
    const float* __restrict__ bias,
    float* __restrict__ h, float* __restrict__ c)
{
    constexpr int SUBS = 256 / H;
    constexpr int RPT  = 8;
    constexpr int TR   = RPT * SUBS;   // 32 rows (H=64), 16 rows (H=128)
    constexpr int G    = 4 * H;
    __shared__ float xls[TR][H];
    __shared__ float hls[TR][H];

    const int row0 = blockIdx.x * TR;
    const int t = threadIdx.x;

    for (int idx = t; idx < TR * H; idx += 256) {
        const int r = idx / H, j = idx % H;
        const int grow = row0 + r;
        float xe;
        if (ENC) {
            const float a0 = xin[grow * 2 + 0];
            const float a1 = xin[grow * 2 + 1];
            xe = fmaxf(0.0f, fmaf(a0, enc_w[j], fmaf(a1, enc_w[H + j], enc_b[j])));
        } else {
            xe = xin[grow * H + j];
        }
        xls[r][j] = xe;
        hls[r][j] = h[grow * H + j];
    }
    __syncthreads();

    const int l   = t % H;
    const int sub = t / H;

    float acc[RPT][4];
    #pragma unroll
    for (int rr = 0; rr < RPT; ++rr) {
        #pragma unroll
        for (int q = 0; q < 4; ++q) acc[rr][q] = bias[q * H + l];
    }

    #pragma unroll 1
    for (int k4 = 0; k4 < H / 4; ++k4) {
        float wih[4][4], whh[4][4];
        #pragma unroll
        for (int j = 0; j < 4; ++j) {
            const int k = k4 * 4 + j;
            #pragma unroll
            for (int q = 0; q < 4; ++q) {
                wih[j][q] = Wih[k * G + q * H + l];
                whh[j][q] = Whh[k * G + q * H + l];
            }
        }
        #pragma unroll
        for (int rr = 0; rr < RPT; ++rr) {
            const int r = sub * RPT + rr;
            const float4 xv = *(reinterpret_cast<const float4*>(&xls[r][0]) + k4);
            const float4 hv = *(reinterpret_cast<const float4*>(&hls[r][0]) + k4);
            #pragma unroll
            for (int q = 0; q < 4; ++q) {
                float a = acc[rr][q];
                a = fmaf(xv.x, wih[0][q], a);
                a = fmaf(xv.y, wih[1][q], a);
                a = fmaf(xv.z, wih[2][q], a);
                a = fmaf(xv.w, wih[3][q], a);
                a = fmaf(hv.x, whh[0][q], a);
                a = fmaf(hv.y, whh[1][q], a);
                a = fmaf(hv.z, whh[2][q], a);
                a = fmaf(hv.w, whh[3][q], a);
                acc[rr][q] = a;
            }
        }
    }

    #pragma unroll
    for (int rr = 0; rr < RPT; ++rr) {
        const int r = sub * RPT + rr;
        const int grow = row0 + r;
        const float ig = sigmoidf_(acc[rr][0]);
        const float fg = sigmoidf_(acc[rr][1]);
        const float gg = tanhf(acc[rr][2]);
        const float og = sigmoidf_(acc[rr][3]);
        const float cold = c[grow * H + l];
        const float c2 = fmaf(fg, cold, ig * gg);
        const float h2 = og * tanhf(c2);
        c[grow * H + l] = c2;
        h[grow * H + l] = h2;
    }
}

// ---- CSR build (once per launch; inc is step-invariant) ----

__global__ __launch_bounds__(256) void count_kernel(
    const int* __restrict__ inc, int* __restrict__ cnt)
{
    const int slot = blockIdx.x * 256 + threadIdx.x;   // 2E slots
    atomicAdd(&cnt[inc[slot]], 1);
}

// Single-block exclusive scan over NN=32768 counts -> ptr[0..NN].
__global__ __launch_bounds__(1024) void scan_kernel(
    const int* __restrict__ cnt, int* __restrict__ ptr)
{
    __shared__ int sums[1024];
    const int t = threadIdx.x;
    const int base = t * 32;
    int local[32];
    int s = 0;
    #pragma unroll
    for (int i = 0; i < 32; ++i) { local[i] = s; s += cnt[base + i]; }
    sums[t] = s;
    __syncthreads();
    // Hillis-Steele inclusive scan of per-thread sums.
    for (int off = 1; off < 1024; off <<= 1) {
        int v = 0;
        if (t >= off) v = sums[t - off];
        __syncthreads();
        sums[t] += v;
        __syncthreads();
    }
    const int excl = sums[t] - s;
    #pragma unroll
    for (int i = 0; i < 32; ++i) ptr[base + i] = excl + local[i];
    if (t == 1023) ptr[NN] = sums[1023];
}

__global__ __launch_bounds__(256) void fill_kernel(
    const int* __restrict__ inc, const int* __restrict__ ptr,
    int* __restrict__ cur, int* __restrict__ rowidx)
{
    const int slot = blockIdx.x * 256 + threadIdx.x;   // 2E slots
    const int n = inc[slot];
    const int pos = atomicAdd(&cur[n], 1);
    rowidx[ptr[n] + pos] = slot >> 1;                  // edge id
}

// ---- per-step aggregation: one wave per node, 64 lanes = 64 hidden cols ----
__global__ __launch_bounds__(256) void gather_kernel(
    const float* __restrict__ hs, const int* __restrict__ ptr,
    const int* __restrict__ rowidx, float* __restrict__ agg)
{
    const int n = blockIdx.x * 4 + (threadIdx.x >> 6);
    const int l = threadIdx.x & 63;
    const int beg = ptr[n];
    const int end = ptr[n + 1];
    float acc = 0.0f;
    for (int i = beg; i < end; ++i) {
        const int e = rowidx[i];
        acc += hs[(size_t)e * 64 + l];
    }
    agg[n * 64 + l] = acc;
}

// x_node[:,0:64] = relu(xn * n_enc_w + n_enc_b)
// x_node[:,64:128] = relu([ht|agg] @ ee_w + ee_b)
__global__ __launch_bounds__(256) void embed_kernel(
    const float* __restrict__ xn, const float* __restrict__ ht,
    const float* __restrict__ agg,
    const float* __restrict__ n_enc_w, const float* __restrict__ n_enc_b,
    const float* __restrict__ ee_w, const float* __restrict__ ee_b,
    float* __restrict__ xnode)
{
    __shared__ float hls[16][64];
    __shared__ float als[16][64];
    const int row0 = blockIdx.x * 16;
    const int t = threadIdx.x;
    for (int idx = t; idx < 16 * 64; idx += 256) {
        const int r = idx >> 6, j = idx & 63;
        hls[r][j] = ht[(row0 + r) * 64 + j];
        als[r][j] = agg[(row0 + r) * 64 + j];
    }
    __syncthreads();

    const int j   = t & 63;
    const int sub = t >> 6;
    float acc[4];
    #pragma unroll
    for (int rr = 0; rr < 4; ++rr) acc[rr] = ee_b[j];

    #pragma unroll 1
    for (int k4 = 0; k4 < 16; ++k4) {
        const float w0 = ee_w[(k4 * 4 + 0) * 64 + j];
        const float w1 = ee_w[(k4 * 4 + 1) * 64 + j];
        const float w2 = ee_w[(k4 * 4 + 2) * 64 + j];
        const float w3 = ee_w[(k4 * 4 + 3) * 64 + j];
        #pragma unroll
        for (int rr = 0; rr < 4; ++rr) {
            const float4 hv = *(reinterpret_cast<const float4*>(&hls[sub * 4 + rr][0]) + k4);
            acc[rr] = fmaf(hv.x, w0, acc[rr]);
            acc[rr] = fmaf(hv.y, w1, acc[rr]);
            acc[rr] = fmaf(hv.z, w2, acc[rr]);
            acc[rr] = fmaf(hv.w, w3, acc[rr]);
        }
    }
    #pragma unroll 1
    for (int k4 = 0; k4 < 16; ++k4) {
        const float w0 = ee_w[(64 + k4 * 4 + 0) * 64 + j];
        const float w1 = ee_w[(64 + k4 * 4 + 1) * 64 + j];
        const float w2 = ee_w[(64 + k4 * 4 + 2) * 64 + j];
        const float w3 = ee_w[(64 + k4 * 4 + 3) * 64 + j];
        #pragma unroll
        for (int rr = 0; rr < 4; ++rr) {
            const float4 av = *(reinterpret_cast<const float4*>(&als[sub * 4 + rr][0]) + k4);
            acc[rr] = fmaf(av.x, w0, acc[rr]);
            acc[rr] = fmaf(av.y, w1, acc[rr]);
            acc[rr] = fmaf(av.z, w2, acc[rr]);
            acc[rr] = fmaf(av.w, w3, acc[rr]);
        }
    }

    #pragma unroll
    for (int rr = 0; rr < 4; ++rr) {
        const int grow = row0 + sub * 4 + rr;
        const float emb = fmaxf(0.0f, acc[rr]);
        const float enc = fmaxf(0.0f, fmaf(xn[grow], n_enc_w[j], n_enc_b[j]));
        xnode[grow * 128 + j]      = enc;
        xnode[grow * 128 + 64 + j] = emb;
    }
}

// out[r] = dot(hn[r,0:128], out_w) + out_b. 4 rows/block, wave per row.
__global__ __launch_bounds__(256) void out_kernel(
    const float* __restrict__ hn, const float* __restrict__ out_w,
    const float* __restrict__ out_b, float* __restrict__ out)
{
    const int r = blockIdx.x * 4 + (threadIdx.x >> 6);
    const int l = threadIdx.x & 63;
    float p = fmaf(hn[r * 128 + l], out_w[l],
                   hn[r * 128 + 64 + l] * out_w[64 + l]);
    #pragma unroll
    for (int off = 32; off > 0; off >>= 1) p += __shfl_down(p, off);
    if (l == 0) out[r] = p + out_b[0];
}

extern "C" void kernel_launch(void* const* d_in, const int* in_sizes, int n_in,
                              void* d_out, int out_size, void* d_ws, size_t ws_size,
                              hipStream_t stream) {
    const float* data_nodes = (const float*)d_in[0];
    const float* data_tE    = (const float*)d_in[1];
    const float* data_sE    = (const float*)d_in[2];
    const float* h_n0 = (const float*)d_in[3];
    const float* c_n0 = (const float*)d_in[4];
    const float* h_t0 = (const float*)d_in[5];
    const float* c_t0 = (const float*)d_in[6];
    const float* h_s0 = (const float*)d_in[7];
    const float* c_s0 = (const float*)d_in[8];
    const int*   inc  = (const int*)d_in[9];
    const float* t_enc_w = (const float*)d_in[10];
    const float* t_enc_b = (const float*)d_in[11];
    const float* t_Wih   = (const float*)d_in[12];
    const float* t_Whh   = (const float*)d_in[13];
    const float* t_b     = (const float*)d_in[14];
    const float* s_enc_w = (const float*)d_in[15];
    const float* s_enc_b = (const float*)d_in[16];
    const float* s_Wih   = (const float*)d_in[17];
    const float* s_Whh   = (const float*)d_in[18];
    const float* s_b     = (const float*)d_in[19];
    const float* n_enc_w = (const float*)d_in[20];
    const float* n_enc_b = (const float*)d_in[21];
    const float* ee_w    = (const float*)d_in[22];
    const float* ee_b    = (const float*)d_in[23];
    const float* n_Wih   = (const float*)d_in[24];
    const float* n_Whh   = (const float*)d_in[25];
    const float* n_b     = (const float*)d_in[26];
    const float* out_w   = (const float*)d_in[27];
    const float* out_b   = (const float*)d_in[28];
    float* out = (float*)d_out;

    // Workspace layout (fp32 + CSR ints): ~139 MB.
    float* p = (float*)d_ws;
    float* ht    = p; p += (size_t)NN * 64;
    float* ct    = p; p += (size_t)NN * 64;
    float* hs    = p; p += (size_t)EE * 64;
    float* cs    = p; p += (size_t)EE * 64;
    float* hn    = p; p += (size_t)NN * 128;
    float* cn    = p; p += (size_t)NN * 128;
    float* agg   = p; p += (size_t)NN * 64;
    float* xnode = p; p += (size_t)NN * 128;
    int* csr_ptr = (int*)p;       // NN+1
    int* csr_row = csr_ptr + (NN + 8);   // 2E
    int* cnt     = csr_row + 2 * EE;     // NN
    int* cur     = cnt + NN;             // NN

    // Initialize recurrent state from inputs (inputs never mutated).
    hipMemcpyAsync(ht, h_t0, (size_t)NN * 64 * 4, hipMemcpyDeviceToDevice, stream);
    hipMemcpyAsync(ct, c_t0, (size_t)NN * 64 * 4, hipMemcpyDeviceToDevice, stream);
    hipMemcpyAsync(hs, h_s0, (size_t)EE * 64 * 4, hipMemcpyDeviceToDevice, stream);
    hipMemcpyAsync(cs, c_s0, (size_t)EE * 64 * 4, hipMemcpyDeviceToDevice, stream);
    hipMemcpyAsync(hn, h_n0, (size_t)NN * 128 * 4, hipMemcpyDeviceToDevice, stream);
    hipMemcpyAsync(cn, c_n0, (size_t)NN * 128 * 4, hipMemcpyDeviceToDevice, stream);

    // Build CSR once (inc is constant across steps).
    hipMemsetAsync(cnt, 0, NN * sizeof(int), stream);
    hipMemsetAsync(cur, 0, NN * sizeof(int), stream);
    count_kernel<<<(2 * EE) / 256, 256, 0, stream>>>(inc, cnt);
    scan_kernel<<<1, 1024, 0, stream>>>(cnt, csr_ptr);
    fill_kernel<<<(2 * EE) / 256, 256, 0, stream>>>(inc, csr_ptr, cur, csr_row);

    for (int st = 0; st < S_LEN; ++st) {
        const float* xt = data_tE + (size_t)st * NN * 2;
        const float* xs = data_sE + (size_t)st * EE * 2;
        const float* xn = data_nodes + (size_t)st * NN;

        lstm_step_kernel<64, 1><<<NN / 32, 256, 0, stream>>>(
            xt, t_enc_w, t_enc_b, t_Wih, t_Whh, t_b, ht, ct);
        lstm_step_kernel<64, 1><<<EE / 32, 256, 0, stream>>>(
            xs, s_enc_w, s_enc_b, s_Wih, s_Whh, s_b, hs, cs);
        gather_kernel<<<NN / 4, 256, 0, stream>>>(hs, csr_ptr, csr_row, agg);
        embed_kernel<<<NN / 16, 256, 0, stream>>>(
            xn, ht, agg, n_enc_w, n_enc_b, ee_w, ee_b, xnode);
        lstm_step_kernel<128, 0><<<NN / 16, 256, 0, stream>>>(
            xnode, nullptr, nullptr, n_Wih, n_Whh, n_b, hn, cn);
        out_kernel<<<NN / 4, 256, 0, stream>>>(hn, out_w, out_b, out + (size_t)st * NN);
    }
}

// Round 3
// 3923.366 us; speedup vs baseline: 2.2462x; 1.4509x over previous
//
#include <hip/hip_runtime.h>
#include <math.h>

// SRNN: S=16 steps, N=32768 nodes, E=131072 spatial edges.
// f16 MFMA gate GEMMs (fp32 accum), h-states stored f16, c-states fp32.
// CSR gather for edge->node aggregation. Workspace ~100 MB.

#define S_LEN 16
#define NN 32768
#define EE 131072

typedef _Float16 f16;
typedef _Float16 f16x8 __attribute__((ext_vector_type(8)));
typedef float f32x4 __attribute__((ext_vector_type(4)));

__device__ __forceinline__ float sigmoidf_(float x) {
    return 1.0f / (1.0f + expf(-x));
}

__device__ __forceinline__ unsigned int pk2(float a, float b) {
    union { f16 h[2]; unsigned int u; } x;
    x.h[0] = (f16)a; x.h[1] = (f16)b;
    return x.u;
}

__device__ __forceinline__ f16x8 ld_frag16(const void* p) {
    union { uint4 v; f16x8 f; } x;
    x.v = *(const uint4*)p;
    return x.f;
}

// ---------------- MFMA LSTM ----------------
// gates = [xenc | h] @ Wt^T + b ; pointwise update. Block = 64 rows, 4 waves.
// Wave w computes rows w*16..w*16+15 across all 4H gate cols.
// A layout: row = lane&15, k = (lane>>4)*8 + j (8 contiguous f16 = ds_read_b128).
// B layout: col = lane&15, same k (from Wt[col][k], 8 contiguous).
// D layout: col = lane&15, row = (lane>>4)*4 + reg  -> gates i/f/g/o lane-local.
template<int H, int ENC>
__global__ __launch_bounds__(256) void lstm_mfma(
    const void* __restrict__ xin,
    const float* __restrict__ enc_w, const float* __restrict__ enc_b,
    const f16* __restrict__ Wt,     // [4H][2H] f16 (k-major rows)
    const float* __restrict__ bias, // [4H]
    f16* __restrict__ h, float* __restrict__ c)
{
    constexpr int K      = 2 * H;      // 128 / 256
    constexpr int KSTEPS = K / 32;     // 4 / 8
    constexpr int NPASS  = H / 64;     // 1 / 2
    constexpr int ROWB   = K * 2;      // LDS bytes per row: 256 / 512
    __shared__ char Xls[64 * ROWB];

    const int row0 = blockIdx.x * 64;
    const int t = threadIdx.x;

    // ---- stage x-part (cols 0..H-1) ----
    if (ENC) {
        const float* xf = (const float*)xin;
        for (int i = t; i < 64 * (H / 2); i += 256) {
            const int r = i / (H / 2), j2 = (i % (H / 2)) * 2;
            const int grow = row0 + r;
            const float x0 = xf[grow * 2 + 0];
            const float x1 = xf[grow * 2 + 1];
            const float e0 = fmaxf(0.f, fmaf(x0, enc_w[j2],     fmaf(x1, enc_w[H + j2],     enc_b[j2])));
            const float e1 = fmaxf(0.f, fmaf(x0, enc_w[j2 + 1], fmaf(x1, enc_w[H + j2 + 1], enc_b[j2 + 1])));
            const int byte = r * ROWB + ((j2 * 2) ^ ((r & 7) << 4));
            *(unsigned int*)(Xls + byte) = pk2(e0, e1);
        }
    } else {
        const f16* xf = (const f16*)xin;
        for (int i = t; i < 64 * (H / 4); i += 256) {
            const int r = i / (H / 4), j4 = (i % (H / 4)) * 4;
            const uint2 v = *(const uint2*)&xf[(size_t)(row0 + r) * H + j4];
            const int byte = r * ROWB + ((j4 * 2) ^ ((r & 7) << 4));
            *(uint2*)(Xls + byte) = v;
        }
    }
    // ---- stage h-part (cols H..2H-1) ----
    for (int i = t; i < 64 * (H / 4); i += 256) {
        const int r = i / (H / 4), j4 = (i % (H / 4)) * 4;
        const uint2 v = *(const uint2*)&h[(size_t)(row0 + r) * H + j4];
        const int byte = r * ROWB + ((H * 2 + j4 * 2) ^ ((r & 7) << 4));
        *(uint2*)(Xls + byte) = v;
    }
    __syncthreads();

    const int wv = t >> 6, l = t & 63;
    const int arow = wv * 16 + (l & 15);
    const char* abase = Xls + arow * ROWB;
    const int kgrp = l >> 4;           // 0..3
    const int lane15 = l & 15;

    f16x8 afrag[KSTEPS];
    #pragma unroll
    for (int ks = 0; ks < KSTEPS; ++ks) {
        const int byte = (ks * 64 + kgrp * 16) ^ ((arow & 7) << 4);
        afrag[ks] = ld_frag16(abase + byte);
    }

    #pragma unroll 1
    for (int p = 0; p < NPASS; ++p) {
        f32x4 acc[4][4];
        #pragma unroll
        for (int q = 0; q < 4; ++q)
            #pragma unroll
            for (int c4 = 0; c4 < 4; ++c4)
                #pragma unroll
                for (int r = 0; r < 4; ++r) acc[q][c4][r] = 0.f;

        #pragma unroll
        for (int q = 0; q < 4; ++q) {
            #pragma unroll
            for (int c4 = 0; c4 < 4; ++c4) {
                const int ct  = q * (4 * NPASS) + p * 4 + c4;
                const int col = ct * 16 + lane15;
                const f16* bp = Wt + (size_t)col * K + kgrp * 8;
                #pragma unroll
                for (int ks = 0; ks < KSTEPS; ++ks) {
                    const f16x8 bfrag = ld_frag16(bp + ks * 32);
                    acc[q][c4] = __builtin_amdgcn_mfma_f32_16x16x32_f16(
                        afrag[ks], bfrag, acc[q][c4], 0, 0, 0);
                }
            }
        }

        // epilogue: gates are lane-local
        #pragma unroll
        for (int c4 = 0; c4 < 4; ++c4) {
            const int lcol = p * 64 + c4 * 16 + lane15;   // hidden index
            const float bi = bias[0 * H + lcol];
            const float bf = bias[1 * H + lcol];
            const float bg = bias[2 * H + lcol];
            const float bo = bias[3 * H + lcol];
            #pragma unroll
            for (int reg = 0; reg < 4; ++reg) {
                const int grow = row0 + wv * 16 + (l >> 4) * 4 + reg;
                const size_t off = (size_t)grow * H + lcol;
                const float ig = sigmoidf_(acc[0][c4][reg] + bi);
                const float fg = sigmoidf_(acc[1][c4][reg] + bf);
                const float gg = tanhf(acc[2][c4][reg] + bg);
                const float og = sigmoidf_(acc[3][c4][reg] + bo);
                const float c2 = fmaf(fg, c[off], ig * gg);
                c[off] = c2;
                h[off] = (f16)(og * tanhf(c2));
            }
        }
    }
}

// ---------------- MFMA embed ----------------
// xnode[:,64:128] = relu([ht|agg] @ ee_w + ee_b)  (MFMA, K=128, 64 out cols)
// xnode[:,0:64]   = relu(xn * n_enc_w + n_enc_b)  (VALU)
__global__ __launch_bounds__(256) void embed_mfma(
    const float* __restrict__ xn,
    const f16* __restrict__ ht, const f16* __restrict__ agg,
    const float* __restrict__ n_enc_w, const float* __restrict__ n_enc_b,
    const f16* __restrict__ Wt_ee,   // [64][128]
    const float* __restrict__ ee_b,
    f16* __restrict__ xnode)
{
    __shared__ char Xls[64 * 256];
    const int row0 = blockIdx.x * 64;
    const int t = threadIdx.x;

    for (int i = t; i < 64 * 16; i += 256) {
        const int r = i / 16, j4 = (i % 16) * 4;
        const uint2 v = *(const uint2*)&ht[(size_t)(row0 + r) * 64 + j4];
        const int byte = r * 256 + ((j4 * 2) ^ ((r & 7) << 4));
        *(uint2*)(Xls + byte) = v;
    }
    for (int i = t; i < 64 * 16; i += 256) {
        const int r = i / 16, j4 = (i % 16) * 4;
        const uint2 v = *(const uint2*)&agg[(size_t)(row0 + r) * 64 + j4];
        const int byte = r * 256 + ((128 + j4 * 2) ^ ((r & 7) << 4));
        *(uint2*)(Xls + byte) = v;
    }
    __syncthreads();

    const int wv = t >> 6, l = t & 63;
    const int arow = wv * 16 + (l & 15);
    const char* abase = Xls + arow * 256;
    const int kgrp = l >> 4;
    const int lane15 = l & 15;

    f16x8 afrag[4];
    #pragma unroll
    for (int ks = 0; ks < 4; ++ks) {
        const int byte = (ks * 64 + kgrp * 16) ^ ((arow & 7) << 4);
        afrag[ks] = ld_frag16(abase + byte);
    }

    f32x4 acc[4];
    #pragma unroll
    for (int c4 = 0; c4 < 4; ++c4)
        #pragma unroll
        for (int r = 0; r < 4; ++r) acc[c4][r] = 0.f;

    #pragma unroll
    for (int c4 = 0; c4 < 4; ++c4) {
        const int col = c4 * 16 + lane15;
        const f16* bp = Wt_ee + (size_t)col * 128 + kgrp * 8;
        #pragma unroll
        for (int ks = 0; ks < 4; ++ks) {
            const f16x8 bfrag = ld_frag16(bp + ks * 32);
            acc[c4] = __builtin_amdgcn_mfma_f32_16x16x32_f16(
                afrag[ks], bfrag, acc[c4], 0, 0, 0);
        }
    }

    #pragma unroll
    for (int c4 = 0; c4 < 4; ++c4) {
        const int col = c4 * 16 + lane15;
        const float bb = ee_b[col];
        #pragma unroll
        for (int reg = 0; reg < 4; ++reg) {
            const int grow = row0 + wv * 16 + (l >> 4) * 4 + reg;
            xnode[(size_t)grow * 128 + 64 + col] = (f16)fmaxf(0.f, acc[c4][reg] + bb);
        }
    }

    // encoder half: cols 0..63
    for (int i = t; i < 64 * 32; i += 256) {
        const int r = i >> 5, j2 = (i & 31) * 2;
        const int grow = row0 + r;
        const float x = xn[grow];
        const float e0 = fmaxf(0.f, fmaf(x, n_enc_w[j2],     n_enc_b[j2]));
        const float e1 = fmaxf(0.f, fmaf(x, n_enc_w[j2 + 1], n_enc_b[j2 + 1]));
        *(unsigned int*)&xnode[(size_t)grow * 128 + j2] = pk2(e0, e1);
    }
}

// ---------------- CSR build (once; inc is step-invariant) ----------------
__global__ __launch_bounds__(256) void count_kernel(
    const int* __restrict__ inc, int* __restrict__ cnt)
{
    const int slot = blockIdx.x * 256 + threadIdx.x;
    atomicAdd(&cnt[inc[slot]], 1);
}

__global__ __launch_bounds__(1024) void scan_kernel(
    const int* __restrict__ cnt, int* __restrict__ ptr)
{
    __shared__ int sums[1024];
    const int t = threadIdx.x;
    const int base = t * 32;
    int local[32];
    int s = 0;
    #pragma unroll
    for (int i = 0; i < 32; ++i) { local[i] = s; s += cnt[base + i]; }
    sums[t] = s;
    __syncthreads();
    for (int off = 1; off < 1024; off <<= 1) {
        int v = 0;
        if (t >= off) v = sums[t - off];
        __syncthreads();
        sums[t] += v;
        __syncthreads();
    }
    const int excl = sums[t] - s;
    #pragma unroll
    for (int i = 0; i < 32; ++i) ptr[base + i] = excl + local[i];
    if (t == 1023) ptr[NN] = sums[1023];
}

__global__ __launch_bounds__(256) void fill_kernel(
    const int* __restrict__ inc, const int* __restrict__ ptr,
    int* __restrict__ cur, int* __restrict__ rowidx)
{
    const int slot = blockIdx.x * 256 + threadIdx.x;
    const int n = inc[slot];
    const int pos = atomicAdd(&cur[n], 1);
    rowidx[ptr[n] + pos] = slot >> 1;
}

// ---------------- gather: 2 nodes per wave, u32 (2×f16) per lane ----------------
__global__ __launch_bounds__(256) void gather_kernel(
    const f16* __restrict__ hs, const int* __restrict__ ptr,
    const int* __restrict__ rowidx, f16* __restrict__ agg)
{
    const int n   = blockIdx.x * 8 + (threadIdx.x >> 5);
    const int l32 = threadIdx.x & 31;
    const int beg = ptr[n];
    const int end = ptr[n + 1];
    const unsigned int* hs32 = (const unsigned int*)hs;
    float a0 = 0.f, a1 = 0.f;
    for (int i = beg; i < end; ++i) {
        const int e = rowidx[i];
        union { unsigned int u; f16 h[2]; } v;
        v.u = hs32[(size_t)e * 32 + l32];
        a0 += (float)v.h[0];
        a1 += (float)v.h[1];
    }
    ((unsigned int*)agg)[(size_t)n * 32 + l32] = pk2(a0, a1);
}

// ---------------- output projection ----------------
__global__ __launch_bounds__(256) void out_kernel(
    const f16* __restrict__ hn, const float* __restrict__ out_w,
    const float* __restrict__ out_b, float* __restrict__ out)
{
    const int r = blockIdx.x * 4 + (threadIdx.x >> 6);
    const int l = threadIdx.x & 63;
    const float a = (float)hn[(size_t)r * 128 + l];
    const float b = (float)hn[(size_t)r * 128 + 64 + l];
    float p = fmaf(a, out_w[l], b * out_w[64 + l]);
    #pragma unroll
    for (int off = 32; off > 0; off >>= 1) p += __shfl_down(p, off);
    if (l == 0) out[r] = p + out_b[0];
}

// ---------------- weight transpose+convert (once) ----------------
// dst[col][k] = (k < Hk ? Wih[k][col] : Whh[k-Hk][col]) as f16. dst is [fourH][K].
__global__ __launch_bounds__(256) void transpose_w_kernel(
    const float* __restrict__ Wih, const float* __restrict__ Whh,
    f16* __restrict__ dst, int Hk, int K, int fourH)
{
    const int tid = blockIdx.x * 256 + threadIdx.x;
    if (tid >= K * fourH) return;
    const int col = tid / K, k = tid % K;
    const float v = (k < Hk) ? Wih[(size_t)k * fourH + col]
                             : Whh[(size_t)(k - Hk) * fourH + col];
    dst[tid] = (f16)v;
}

// f32 -> f16 (packed u32 stores), n2 = n/2
__global__ __launch_bounds__(256) void cvt_kernel(
    const float* __restrict__ src, f16* __restrict__ dst, int n2)
{
    const int i = blockIdx.x * 256 + threadIdx.x;
    if (i >= n2) return;
    const float2 v = ((const float2*)src)[i];
    ((unsigned int*)dst)[i] = pk2(v.x, v.y);
}

extern "C" void kernel_launch(void* const* d_in, const int* in_sizes, int n_in,
                              void* d_out, int out_size, void* d_ws, size_t ws_size,
                              hipStream_t stream) {
    const float* data_nodes = (const float*)d_in[0];
    const float* data_tE    = (const float*)d_in[1];
    const float* data_sE    = (const float*)d_in[2];
    const float* h_n0 = (const float*)d_in[3];
    const float* c_n0 = (const float*)d_in[4];
    const float* h_t0 = (const float*)d_in[5];
    const float* c_t0 = (const float*)d_in[6];
    const float* h_s0 = (const float*)d_in[7];
    const float* c_s0 = (const float*)d_in[8];
    const int*   inc  = (const int*)d_in[9];
    const float* t_enc_w = (const float*)d_in[10];
    const float* t_enc_b = (const float*)d_in[11];
    const float* t_Wih   = (const float*)d_in[12];
    const float* t_Whh   = (const float*)d_in[13];
    const float* t_b     = (const float*)d_in[14];
    const float* s_enc_w = (const float*)d_in[15];
    const float* s_enc_b = (const float*)d_in[16];
    const float* s_Wih   = (const float*)d_in[17];
    const float* s_Whh   = (const float*)d_in[18];
    const float* s_b     = (const float*)d_in[19];
    const float* n_enc_w = (const float*)d_in[20];
    const float* n_enc_b = (const float*)d_in[21];
    const float* ee_w    = (const float*)d_in[22];
    const float* ee_b    = (const float*)d_in[23];
    const float* n_Wih   = (const float*)d_in[24];
    const float* n_Whh   = (const float*)d_in[25];
    const float* n_b     = (const float*)d_in[26];
    const float* out_w   = (const float*)d_in[27];
    const float* out_b   = (const float*)d_in[28];
    float* out = (float*)d_out;

    // ---- workspace layout ----
    char* p = (char*)d_ws;
    f16*  ht16    = (f16*)p;  p += (size_t)NN * 64 * 2;     // 4 MB
    f16*  hs16    = (f16*)p;  p += (size_t)EE * 64 * 2;     // 16 MB
    f16*  hn16    = (f16*)p;  p += (size_t)NN * 128 * 2;    // 8 MB
    f16*  agg16   = (f16*)p;  p += (size_t)NN * 64 * 2;     // 4 MB
    f16*  xnode16 = (f16*)p;  p += (size_t)NN * 128 * 2;    // 8 MB
    float* ct     = (float*)p; p += (size_t)NN * 64 * 4;    // 8 MB
    float* cs     = (float*)p; p += (size_t)EE * 64 * 4;    // 33.5 MB
    float* cn     = (float*)p; p += (size_t)NN * 128 * 4;   // 16.8 MB
    f16*  Wt_t    = (f16*)p;  p += (size_t)256 * 128 * 2;   // 64 KB
    f16*  Wt_s    = (f16*)p;  p += (size_t)256 * 128 * 2;   // 64 KB
    f16*  Wt_n    = (f16*)p;  p += (size_t)512 * 256 * 2;   // 256 KB
    f16*  Wt_ee   = (f16*)p;  p += (size_t)64 * 128 * 2;    // 16 KB
    int*  csr_ptr = (int*)p;  p += (size_t)(NN + 8) * 4;
    int*  csr_row = (int*)p;  p += (size_t)2 * EE * 4;
    int*  cnt     = (int*)p;  p += (size_t)NN * 4;
    int*  cur     = (int*)p;  p += (size_t)NN * 4;

    // ---- one-time per launch: state init, weight conversion, CSR ----
    cvt_kernel<<<(NN * 64 / 2 + 255) / 256, 256, 0, stream>>>(h_t0, ht16, NN * 64 / 2);
    cvt_kernel<<<(EE * 64 / 2 + 255) / 256, 256, 0, stream>>>(h_s0, hs16, EE * 64 / 2);
    cvt_kernel<<<(NN * 128 / 2 + 255) / 256, 256, 0, stream>>>(h_n0, hn16, NN * 128 / 2);
    hipMemcpyAsync(ct, c_t0, (size_t)NN * 64 * 4, hipMemcpyDeviceToDevice, stream);
    hipMemcpyAsync(cs, c_s0, (size_t)EE * 64 * 4, hipMemcpyDeviceToDevice, stream);
    hipMemcpyAsync(cn, c_n0, (size_t)NN * 128 * 4, hipMemcpyDeviceToDevice, stream);

    transpose_w_kernel<<<(256 * 128 + 255) / 256, 256, 0, stream>>>(t_Wih, t_Whh, Wt_t, 64, 128, 256);
    transpose_w_kernel<<<(256 * 128 + 255) / 256, 256, 0, stream>>>(s_Wih, s_Whh, Wt_s, 64, 128, 256);
    transpose_w_kernel<<<(512 * 256 + 255) / 256, 256, 0, stream>>>(n_Wih, n_Whh, Wt_n, 128, 256, 512);
    transpose_w_kernel<<<(64 * 128 + 255) / 256, 256, 0, stream>>>(ee_w, ee_w, Wt_ee, 128, 128, 64);

    hipMemsetAsync(cnt, 0, NN * sizeof(int), stream);
    hipMemsetAsync(cur, 0, NN * sizeof(int), stream);
    count_kernel<<<(2 * EE) / 256, 256, 0, stream>>>(inc, cnt);
    scan_kernel<<<1, 1024, 0, stream>>>(cnt, csr_ptr);
    fill_kernel<<<(2 * EE) / 256, 256, 0, stream>>>(inc, csr_ptr, cur, csr_row);

    for (int st = 0; st < S_LEN; ++st) {
        const float* xt = data_tE + (size_t)st * NN * 2;
        const float* xs = data_sE + (size_t)st * EE * 2;
        const float* xn = data_nodes + (size_t)st * NN;

        lstm_mfma<64, 1><<<NN / 64, 256, 0, stream>>>(
            xt, t_enc_w, t_enc_b, Wt_t, t_b, ht16, ct);
        lstm_mfma<64, 1><<<EE / 64, 256, 0, stream>>>(
            xs, s_enc_w, s_enc_b, Wt_s, s_b, hs16, cs);
        gather_kernel<<<NN / 8, 256, 0, stream>>>(hs16, csr_ptr, csr_row, agg16);
        embed_mfma<<<NN / 64, 256, 0, stream>>>(
            xn, ht16, agg16, n_enc_w, n_enc_b, Wt_ee, ee_b, xnode16);
        lstm_mfma<128, 0><<<NN / 64, 256, 0, stream>>>(
            xnode16, nullptr, nullptr, Wt_n, n_b, hn16, cn);
        out_kernel<<<NN / 4, 256, 0, stream>>>(hn16, out_w, out_b, out + (size_t)st * NN);
    }
}

// Round 4
// 1944.976 us; speedup vs baseline: 4.5310x; 2.0172x over previous
//
#include <hip/hip_runtime.h>
#include <math.h>

// SRNN: S=16 steps, N=32768 nodes, E=131072 spatial edges.
// f16 MFMA gate GEMMs with REGISTER-RESIDENT weights (each wave owns 16
// hidden cols, holds all its B-fragments in VGPRs for the whole kernel),
// fast exp2-based gate nonlinearities. h-states f16, c-states fp32.

#define S_LEN 16
#define NN 32768
#define EE 131072

typedef _Float16 f16;
typedef _Float16 f16x8 __attribute__((ext_vector_type(8)));
typedef float f32x4 __attribute__((ext_vector_type(4)));

__device__ __forceinline__ float fsigmoid(float x) {
    // 1/(1+2^(-x*log2e)); v_exp_f32 + v_rcp_f32
    return __builtin_amdgcn_rcpf(1.0f + __builtin_amdgcn_exp2f(-1.44269504f * x));
}
__device__ __forceinline__ float ftanh(float x) {
    // (e-1)/(e+1) with e=2^(2x*log2e); saturates correctly at +-inf
    const float e = __builtin_amdgcn_exp2f(2.88539008f * x);
    return 1.0f - 2.0f * __builtin_amdgcn_rcpf(e + 1.0f);
}

__device__ __forceinline__ unsigned int pk2(float a, float b) {
    union { f16 h[2]; unsigned int u; } x;
    x.h[0] = (f16)a; x.h[1] = (f16)b;
    return x.u;
}

__device__ __forceinline__ f16x8 ld_frag16(const void* p) {
    union { uint4 v; f16x8 f; } x;
    x.v = *(const uint4*)p;
    return x.f;
}

// ---------------- MFMA LSTM, B-resident ----------------
// gates = [xenc | h] @ Wt^T + b. Block = WPB waves, TR=128 rows.
// Wave wv owns hidden cols [16wv,16wv+16) for ALL 4 gates; its B-fragments
// (4 gates x KSTEPS) are loaded once and stay in VGPRs.
// MFMA 16x16x32 layouts (bench-verified in round 3):
//   A: row=lane&15, k=(lane>>4)*8+j ; B: col=lane&15, same k
//   D: col=lane&15, row=(lane>>4)*4+reg  -> gates i/f/g/o lane-local.
template<int H, int ENC, int WPB>
__global__ __launch_bounds__(WPB * 64) void lstm_mfma(
    const void* __restrict__ xin,
    const float* __restrict__ enc_w, const float* __restrict__ enc_b,
    const f16* __restrict__ Wt,     // [4H][2H] f16 (k-major rows)
    const float* __restrict__ bias, // [4H]
    f16* __restrict__ h, float* __restrict__ c)
{
    constexpr int K       = 2 * H;       // 128 / 256
    constexpr int KSTEPS  = K / 32;      // 4 / 8
    constexpr int ROWB    = K * 2;       // LDS bytes per row
    constexpr int TR      = 128;
    constexpr int THREADS = WPB * 64;
    __shared__ char Xls[TR * ROWB];

    const int row0 = blockIdx.x * TR;
    const int t = threadIdx.x;
    const int wv = t >> 6, l = t & 63;
    const int lane15 = l & 15, kgrp = l >> 4;

    // ---- B fragments: load once, keep in VGPRs ----
    f16x8 bfrag[4][KSTEPS];
    #pragma unroll
    for (int q = 0; q < 4; ++q) {
        const int col = q * H + wv * 16 + lane15;
        const f16* bp = Wt + (size_t)col * K + kgrp * 8;
        #pragma unroll
        for (int ks = 0; ks < KSTEPS; ++ks)
            bfrag[q][ks] = ld_frag16(bp + ks * 32);
    }

    // ---- stage x-part (cols 0..H-1) ----
    if (ENC) {
        const float* xf = (const float*)xin;
        for (int i = t; i < TR * (H / 2); i += THREADS) {
            const int r = i / (H / 2), j2 = (i % (H / 2)) * 2;
            const int grow = row0 + r;
            const float x0 = xf[grow * 2 + 0];
            const float x1 = xf[grow * 2 + 1];
            const float e0 = fmaxf(0.f, fmaf(x0, enc_w[j2],     fmaf(x1, enc_w[H + j2],     enc_b[j2])));
            const float e1 = fmaxf(0.f, fmaf(x0, enc_w[j2 + 1], fmaf(x1, enc_w[H + j2 + 1], enc_b[j2 + 1])));
            const int byte = r * ROWB + ((j2 * 2) ^ ((r & 7) << 4));
            *(unsigned int*)(Xls + byte) = pk2(e0, e1);
        }
    } else {
        const f16* xf = (const f16*)xin;
        for (int i = t; i < TR * (H / 4); i += THREADS) {
            const int r = i / (H / 4), j4 = (i % (H / 4)) * 4;
            const uint2 v = *(const uint2*)&xf[(size_t)(row0 + r) * H + j4];
            const int byte = r * ROWB + ((j4 * 2) ^ ((r & 7) << 4));
            *(uint2*)(Xls + byte) = v;
        }
    }
    // ---- stage h-part (cols H..2H-1) ----
    for (int i = t; i < TR * (H / 4); i += THREADS) {
        const int r = i / (H / 4), j4 = (i % (H / 4)) * 4;
        const uint2 v = *(const uint2*)&h[(size_t)(row0 + r) * H + j4];
        const int byte = r * ROWB + ((H * 2 + j4 * 2) ^ ((r & 7) << 4));
        *(uint2*)(Xls + byte) = v;
    }
    __syncthreads();

    const int col = wv * 16 + lane15;        // owned hidden column
    const float bi = bias[0 * H + col];
    const float bf = bias[1 * H + col];
    const float bg = bias[2 * H + col];
    const float bo = bias[3 * H + col];

    #pragma unroll
    for (int rt = 0; rt < TR / 16; ++rt) {
        const int arow = rt * 16 + lane15;
        const char* abase = Xls + arow * ROWB;
        f16x8 afrag[KSTEPS];
        #pragma unroll
        for (int ks = 0; ks < KSTEPS; ++ks) {
            const int byte = (ks * 64 + kgrp * 16) ^ ((arow & 7) << 4);
            afrag[ks] = ld_frag16(abase + byte);
        }

        f32x4 acc[4];
        #pragma unroll
        for (int q = 0; q < 4; ++q)
            #pragma unroll
            for (int r = 0; r < 4; ++r) acc[q][r] = 0.f;

        #pragma unroll
        for (int ks = 0; ks < KSTEPS; ++ks)
            #pragma unroll
            for (int q = 0; q < 4; ++q)
                acc[q] = __builtin_amdgcn_mfma_f32_16x16x32_f16(
                    afrag[ks], bfrag[q][ks], acc[q], 0, 0, 0);

        #pragma unroll
        for (int reg = 0; reg < 4; ++reg) {
            const int grow = row0 + rt * 16 + (l >> 4) * 4 + reg;
            const size_t off = (size_t)grow * H + col;
            const float ig = fsigmoid(acc[0][reg] + bi);
            const float fg = fsigmoid(acc[1][reg] + bf);
            const float gg = ftanh(acc[2][reg] + bg);
            const float og = fsigmoid(acc[3][reg] + bo);
            const float c2 = fmaf(fg, c[off], ig * gg);
            c[off] = c2;
            h[off] = (f16)(og * ftanh(c2));
        }
    }
}

// ---------------- MFMA embed, B-resident ----------------
// xnode[:,64:128] = relu([ht|agg] @ ee_w + ee_b); xnode[:,0:64] = relu(enc).
__global__ __launch_bounds__(256) void embed_mfma(
    const float* __restrict__ xn,
    const f16* __restrict__ ht, const f16* __restrict__ agg,
    const float* __restrict__ n_enc_w, const float* __restrict__ n_enc_b,
    const f16* __restrict__ Wt_ee,   // [64][128]
    const float* __restrict__ ee_b,
    f16* __restrict__ xnode)
{
    constexpr int TR = 128;
    __shared__ char Xls[TR * 256];
    const int row0 = blockIdx.x * TR;
    const int t = threadIdx.x;
    const int wv = t >> 6, l = t & 63;
    const int lane15 = l & 15, kgrp = l >> 4;

    // B fragments (1 col-tile per wave), resident
    const int col = wv * 16 + lane15;
    f16x8 bfrag[4];
    {
        const f16* bp = Wt_ee + (size_t)col * 128 + kgrp * 8;
        #pragma unroll
        for (int ks = 0; ks < 4; ++ks) bfrag[ks] = ld_frag16(bp + ks * 32);
    }

    for (int i = t; i < TR * 16; i += 256) {
        const int r = i / 16, j4 = (i % 16) * 4;
        const uint2 v = *(const uint2*)&ht[(size_t)(row0 + r) * 64 + j4];
        const int byte = r * 256 + ((j4 * 2) ^ ((r & 7) << 4));
        *(uint2*)(Xls + byte) = v;
    }
    for (int i = t; i < TR * 16; i += 256) {
        const int r = i / 16, j4 = (i % 16) * 4;
        const uint2 v = *(const uint2*)&agg[(size_t)(row0 + r) * 64 + j4];
        const int byte = r * 256 + ((128 + j4 * 2) ^ ((r & 7) << 4));
        *(uint2*)(Xls + byte) = v;
    }
    __syncthreads();

    const float bb = ee_b[col];
    #pragma unroll
    for (int rt = 0; rt < TR / 16; ++rt) {
        const int arow = rt * 16 + lane15;
        const char* abase = Xls + arow * 256;
        f16x8 afrag[4];
        #pragma unroll
        for (int ks = 0; ks < 4; ++ks) {
            const int byte = (ks * 64 + kgrp * 16) ^ ((arow & 7) << 4);
            afrag[ks] = ld_frag16(abase + byte);
        }
        f32x4 acc;
        #pragma unroll
        for (int r = 0; r < 4; ++r) acc[r] = 0.f;
        #pragma unroll
        for (int ks = 0; ks < 4; ++ks)
            acc = __builtin_amdgcn_mfma_f32_16x16x32_f16(afrag[ks], bfrag[ks], acc, 0, 0, 0);
        #pragma unroll
        for (int reg = 0; reg < 4; ++reg) {
            const int grow = row0 + rt * 16 + (l >> 4) * 4 + reg;
            xnode[(size_t)grow * 128 + 64 + col] = (f16)fmaxf(0.f, acc[reg] + bb);
        }
    }

    // encoder half: cols 0..63
    for (int i = t; i < TR * 32; i += 256) {
        const int r = i >> 5, j2 = (i & 31) * 2;
        const int grow = row0 + r;
        const float x = xn[grow];
        const float e0 = fmaxf(0.f, fmaf(x, n_enc_w[j2],     n_enc_b[j2]));
        const float e1 = fmaxf(0.f, fmaf(x, n_enc_w[j2 + 1], n_enc_b[j2 + 1]));
        *(unsigned int*)&xnode[(size_t)grow * 128 + j2] = pk2(e0, e1);
    }
}

// ---------------- CSR build (once; inc is step-invariant) ----------------
__global__ __launch_bounds__(256) void count_kernel(
    const int* __restrict__ inc, int* __restrict__ cnt)
{
    const int slot = blockIdx.x * 256 + threadIdx.x;
    atomicAdd(&cnt[inc[slot]], 1);
}

__global__ __launch_bounds__(1024) void scan_kernel(
    const int* __restrict__ cnt, int* __restrict__ ptr)
{
    __shared__ int sums[1024];
    const int t = threadIdx.x;
    const int base = t * 32;
    int local[32];
    int s = 0;
    #pragma unroll
    for (int i = 0; i < 32; ++i) { local[i] = s; s += cnt[base + i]; }
    sums[t] = s;
    __syncthreads();
    for (int off = 1; off < 1024; off <<= 1) {
        int v = 0;
        if (t >= off) v = sums[t - off];
        __syncthreads();
        sums[t] += v;
        __syncthreads();
    }
    const int excl = sums[t] - s;
    #pragma unroll
    for (int i = 0; i < 32; ++i) ptr[base + i] = excl + local[i];
    if (t == 1023) ptr[NN] = sums[1023];
}

__global__ __launch_bounds__(256) void fill_kernel(
    const int* __restrict__ inc, const int* __restrict__ ptr,
    int* __restrict__ cur, int* __restrict__ rowidx)
{
    const int slot = blockIdx.x * 256 + threadIdx.x;
    const int n = inc[slot];
    const int pos = atomicAdd(&cur[n], 1);
    rowidx[ptr[n] + pos] = slot >> 1;
}

// ---------------- gather: 2 nodes per wave, u32 (2xf16) per lane ----------------
__global__ __launch_bounds__(256) void gather_kernel(
    const f16* __restrict__ hs, const int* __restrict__ ptr,
    const int* __restrict__ rowidx, f16* __restrict__ agg)
{
    const int n   = blockIdx.x * 8 + (threadIdx.x >> 5);
    const int l32 = threadIdx.x & 31;
    const int beg = ptr[n];
    const int end = ptr[n + 1];
    const unsigned int* hs32 = (const unsigned int*)hs;
    float a0 = 0.f, a1 = 0.f;
    for (int i = beg; i < end; ++i) {
        const int e = rowidx[i];
        union { unsigned int u; f16 h[2]; } v;
        v.u = hs32[(size_t)e * 32 + l32];
        a0 += (float)v.h[0];
        a1 += (float)v.h[1];
    }
    ((unsigned int*)agg)[(size_t)n * 32 + l32] = pk2(a0, a1);
}

// ---------------- output projection ----------------
__global__ __launch_bounds__(256) void out_kernel(
    const f16* __restrict__ hn, const float* __restrict__ out_w,
    const float* __restrict__ out_b, float* __restrict__ out)
{
    const int r = blockIdx.x * 4 + (threadIdx.x >> 6);
    const int l = threadIdx.x & 63;
    const float a = (float)hn[(size_t)r * 128 + l];
    const float b = (float)hn[(size_t)r * 128 + 64 + l];
    float p = fmaf(a, out_w[l], b * out_w[64 + l]);
    #pragma unroll
    for (int off = 32; off > 0; off >>= 1) p += __shfl_down(p, off);
    if (l == 0) out[r] = p + out_b[0];
}

// ---------------- weight transpose+convert (once) ----------------
__global__ __launch_bounds__(256) void transpose_w_kernel(
    const float* __restrict__ Wih, const float* __restrict__ Whh,
    f16* __restrict__ dst, int Hk, int K, int fourH)
{
    const int tid = blockIdx.x * 256 + threadIdx.x;
    if (tid >= K * fourH) return;
    const int col = tid / K, k = tid % K;
    const float v = (k < Hk) ? Wih[(size_t)k * fourH + col]
                             : Whh[(size_t)(k - Hk) * fourH + col];
    dst[tid] = (f16)v;
}

__global__ __launch_bounds__(256) void cvt_kernel(
    const float* __restrict__ src, f16* __restrict__ dst, int n2)
{
    const int i = blockIdx.x * 256 + threadIdx.x;
    if (i >= n2) return;
    const float2 v = ((const float2*)src)[i];
    ((unsigned int*)dst)[i] = pk2(v.x, v.y);
}

extern "C" void kernel_launch(void* const* d_in, const int* in_sizes, int n_in,
                              void* d_out, int out_size, void* d_ws, size_t ws_size,
                              hipStream_t stream) {
    const float* data_nodes = (const float*)d_in[0];
    const float* data_tE    = (const float*)d_in[1];
    const float* data_sE    = (const float*)d_in[2];
    const float* h_n0 = (const float*)d_in[3];
    const float* c_n0 = (const float*)d_in[4];
    const float* h_t0 = (const float*)d_in[5];
    const float* c_t0 = (const float*)d_in[6];
    const float* h_s0 = (const float*)d_in[7];
    const float* c_s0 = (const float*)d_in[8];
    const int*   inc  = (const int*)d_in[9];
    const float* t_enc_w = (const float*)d_in[10];
    const float* t_enc_b = (const float*)d_in[11];
    const float* t_Wih   = (const float*)d_in[12];
    const float* t_Whh   = (const float*)d_in[13];
    const float* t_b     = (const float*)d_in[14];
    const float* s_enc_w = (const float*)d_in[15];
    const float* s_enc_b = (const float*)d_in[16];
    const float* s_Wih   = (const float*)d_in[17];
    const float* s_Whh   = (const float*)d_in[18];
    const float* s_b     = (const float*)d_in[19];
    const float* n_enc_w = (const float*)d_in[20];
    const float* n_enc_b = (const float*)d_in[21];
    const float* ee_w    = (const float*)d_in[22];
    const float* ee_b    = (const float*)d_in[23];
    const float* n_Wih   = (const float*)d_in[24];
    const float* n_Whh   = (const float*)d_in[25];
    const float* n_b     = (const float*)d_in[26];
    const float* out_w   = (const float*)d_in[27];
    const float* out_b   = (const float*)d_in[28];
    float* out = (float*)d_out;

    // ---- workspace layout ----
    char* p = (char*)d_ws;
    f16*  ht16    = (f16*)p;  p += (size_t)NN * 64 * 2;
    f16*  hs16    = (f16*)p;  p += (size_t)EE * 64 * 2;
    f16*  hn16    = (f16*)p;  p += (size_t)NN * 128 * 2;
    f16*  agg16   = (f16*)p;  p += (size_t)NN * 64 * 2;
    f16*  xnode16 = (f16*)p;  p += (size_t)NN * 128 * 2;
    float* ct     = (float*)p; p += (size_t)NN * 64 * 4;
    float* cs     = (float*)p; p += (size_t)EE * 64 * 4;
    float* cn     = (float*)p; p += (size_t)NN * 128 * 4;
    f16*  Wt_t    = (f16*)p;  p += (size_t)256 * 128 * 2;
    f16*  Wt_s    = (f16*)p;  p += (size_t)256 * 128 * 2;
    f16*  Wt_n    = (f16*)p;  p += (size_t)512 * 256 * 2;
    f16*  Wt_ee   = (f16*)p;  p += (size_t)64 * 128 * 2;
    int*  csr_ptr = (int*)p;  p += (size_t)(NN + 8) * 4;
    int*  csr_row = (int*)p;  p += (size_t)2 * EE * 4;
    int*  cnt     = (int*)p;  p += (size_t)NN * 4;
    int*  cur     = (int*)p;  p += (size_t)NN * 4;

    // ---- one-time: state init, weight conversion, CSR ----
    cvt_kernel<<<(NN * 64 / 2 + 255) / 256, 256, 0, stream>>>(h_t0, ht16, NN * 64 / 2);
    cvt_kernel<<<(EE * 64 / 2 + 255) / 256, 256, 0, stream>>>(h_s0, hs16, EE * 64 / 2);
    cvt_kernel<<<(NN * 128 / 2 + 255) / 256, 256, 0, stream>>>(h_n0, hn16, NN * 128 / 2);
    hipMemcpyAsync(ct, c_t0, (size_t)NN * 64 * 4, hipMemcpyDeviceToDevice, stream);
    hipMemcpyAsync(cs, c_s0, (size_t)EE * 64 * 4, hipMemcpyDeviceToDevice, stream);
    hipMemcpyAsync(cn, c_n0, (size_t)NN * 128 * 4, hipMemcpyDeviceToDevice, stream);

    transpose_w_kernel<<<(256 * 128 + 255) / 256, 256, 0, stream>>>(t_Wih, t_Whh, Wt_t, 64, 128, 256);
    transpose_w_kernel<<<(256 * 128 + 255) / 256, 256, 0, stream>>>(s_Wih, s_Whh, Wt_s, 64, 128, 256);
    transpose_w_kernel<<<(512 * 256 + 255) / 256, 256, 0, stream>>>(n_Wih, n_Whh, Wt_n, 128, 256, 512);
    transpose_w_kernel<<<(64 * 128 + 255) / 256, 256, 0, stream>>>(ee_w, ee_w, Wt_ee, 128, 128, 64);

    hipMemsetAsync(cnt, 0, NN * sizeof(int), stream);
    hipMemsetAsync(cur, 0, NN * sizeof(int), stream);
    count_kernel<<<(2 * EE) / 256, 256, 0, stream>>>(inc, cnt);
    scan_kernel<<<1, 1024, 0, stream>>>(cnt, csr_ptr);
    fill_kernel<<<(2 * EE) / 256, 256, 0, stream>>>(inc, csr_ptr, cur, csr_row);

    for (int st = 0; st < S_LEN; ++st) {
        const float* xt = data_tE + (size_t)st * NN * 2;
        const float* xs = data_sE + (size_t)st * EE * 2;
        const float* xn = data_nodes + (size_t)st * NN;

        lstm_mfma<64, 1, 4><<<NN / 128, 256, 0, stream>>>(
            xt, t_enc_w, t_enc_b, Wt_t, t_b, ht16, ct);
        lstm_mfma<64, 1, 4><<<EE / 128, 256, 0, stream>>>(
            xs, s_enc_w, s_enc_b, Wt_s, s_b, hs16, cs);
        gather_kernel<<<NN / 8, 256, 0, stream>>>(hs16, csr_ptr, csr_row, agg16);
        embed_mfma<<<NN / 128, 256, 0, stream>>>(
            xn, ht16, agg16, n_enc_w, n_enc_b, Wt_ee, ee_b, xnode16);
        lstm_mfma<128, 0, 8><<<NN / 128, 512, 0, stream>>>(
            xnode16, nullptr, nullptr, Wt_n, n_b, hn16, cn);
        out_kernel<<<NN / 4, 256, 0, stream>>>(hn16, out_w, out_b, out + (size_t)st * NN);
    }
}

// Round 5
// 1658.959 us; speedup vs baseline: 5.3122x; 1.1724x over previous
//
#include <hip/hip_runtime.h>
#include <math.h>

// SRNN: S=16 steps, N=32768 nodes, E=131072 spatial edges.
// f16 MFMA gate GEMMs, B-resident weights. Fusions: temporal+spatial edge
// LSTMs in one dispatch; CSR gather fused into embed (agg never hits global).
// h-states f16, c-states fp32. Math identical to round 4 (absmax margin thin).

#define S_LEN 16
#define NN 32768
#define EE 131072

typedef _Float16 f16;
typedef _Float16 f16x8 __attribute__((ext_vector_type(8)));
typedef float f32x4 __attribute__((ext_vector_type(4)));

__device__ __forceinline__ float fsigmoid(float x) {
    return __builtin_amdgcn_rcpf(1.0f + __builtin_amdgcn_exp2f(-1.44269504f * x));
}
__device__ __forceinline__ float ftanh(float x) {
    const float e = __builtin_amdgcn_exp2f(2.88539008f * x);
    return 1.0f - 2.0f * __builtin_amdgcn_rcpf(e + 1.0f);
}

__device__ __forceinline__ unsigned int pk2(float a, float b) {
    union { f16 h[2]; unsigned int u; } x;
    x.h[0] = (f16)a; x.h[1] = (f16)b;
    return x.u;
}

__device__ __forceinline__ f16x8 ld_frag16(const void* p) {
    union { uint4 v; f16x8 f; } x;
    x.v = *(const uint4*)p;
    return x.f;
}

// ---------------- fused edge LSTM (temporal + spatial), H=64 ----------------
// Blocks [0, NN/64) -> temporal rows; blocks [NN/64, NN/64+EE/64) -> spatial.
// TR=64 rows/block, 4 waves. Wave wv owns hidden cols [16wv,16wv+16) for all
// 4 gates; B-fragments resident in VGPRs (16 x f16x8).
__global__ __launch_bounds__(256) void edge_lstm_fused(
    const float* __restrict__ xT, const float* __restrict__ xS,
    const float* __restrict__ t_enc_w, const float* __restrict__ t_enc_b,
    const float* __restrict__ s_enc_w, const float* __restrict__ s_enc_b,
    const f16* __restrict__ WtT, const f16* __restrict__ WtS,
    const float* __restrict__ biasT, const float* __restrict__ biasS,
    f16* __restrict__ hT, float* __restrict__ cT,
    f16* __restrict__ hS, float* __restrict__ cS)
{
    constexpr int H = 64, K = 128, KSTEPS = 4, ROWB = 256, TR = 64;
    __shared__ char Xls[TR * ROWB];

    const int bT = NN / TR;
    const bool isT = (int)blockIdx.x < bT;
    const int row0 = (isT ? blockIdx.x : blockIdx.x - bT) * TR;
    const float* xf    = isT ? xT : xS;
    const float* enc_w = isT ? t_enc_w : s_enc_w;
    const float* enc_b = isT ? t_enc_b : s_enc_b;
    const f16*   Wt    = isT ? WtT : WtS;
    const float* bias  = isT ? biasT : biasS;
    f16*   h = isT ? hT : hS;
    float* c = isT ? cT : cS;

    const int t = threadIdx.x;
    const int wv = t >> 6, l = t & 63;
    const int lane15 = l & 15, kgrp = l >> 4;

    // B fragments: resident
    f16x8 bfrag[4][KSTEPS];
    #pragma unroll
    for (int q = 0; q < 4; ++q) {
        const int col = q * H + wv * 16 + lane15;
        const f16* bp = Wt + (size_t)col * K + kgrp * 8;
        #pragma unroll
        for (int ks = 0; ks < KSTEPS; ++ks)
            bfrag[q][ks] = ld_frag16(bp + ks * 32);
    }

    // stage x-enc (cols 0..63)
    for (int i = t; i < TR * (H / 2); i += 256) {
        const int r = i / (H / 2), j2 = (i % (H / 2)) * 2;
        const int grow = row0 + r;
        const float x0 = xf[grow * 2 + 0];
        const float x1 = xf[grow * 2 + 1];
        const float e0 = fmaxf(0.f, fmaf(x0, enc_w[j2],     fmaf(x1, enc_w[H + j2],     enc_b[j2])));
        const float e1 = fmaxf(0.f, fmaf(x0, enc_w[j2 + 1], fmaf(x1, enc_w[H + j2 + 1], enc_b[j2 + 1])));
        const int byte = r * ROWB + ((j2 * 2) ^ ((r & 7) << 4));
        *(unsigned int*)(Xls + byte) = pk2(e0, e1);
    }
    // stage h (cols 64..127)
    for (int i = t; i < TR * (H / 4); i += 256) {
        const int r = i / (H / 4), j4 = (i % (H / 4)) * 4;
        const uint2 v = *(const uint2*)&h[(size_t)(row0 + r) * H + j4];
        const int byte = r * ROWB + ((H * 2 + j4 * 2) ^ ((r & 7) << 4));
        *(uint2*)(Xls + byte) = v;
    }
    __syncthreads();

    const int col = wv * 16 + lane15;
    const float bi = bias[0 * H + col];
    const float bf = bias[1 * H + col];
    const float bg = bias[2 * H + col];
    const float bo = bias[3 * H + col];

    #pragma unroll
    for (int rt = 0; rt < TR / 16; ++rt) {
        const int arow = rt * 16 + lane15;
        const char* abase = Xls + arow * ROWB;
        f16x8 afrag[KSTEPS];
        #pragma unroll
        for (int ks = 0; ks < KSTEPS; ++ks) {
            const int byte = (ks * 64 + kgrp * 16) ^ ((arow & 7) << 4);
            afrag[ks] = ld_frag16(abase + byte);
        }
        f32x4 acc[4];
        #pragma unroll
        for (int q = 0; q < 4; ++q)
            #pragma unroll
            for (int r = 0; r < 4; ++r) acc[q][r] = 0.f;
        #pragma unroll
        for (int ks = 0; ks < KSTEPS; ++ks)
            #pragma unroll
            for (int q = 0; q < 4; ++q)
                acc[q] = __builtin_amdgcn_mfma_f32_16x16x32_f16(
                    afrag[ks], bfrag[q][ks], acc[q], 0, 0, 0);
        #pragma unroll
        for (int reg = 0; reg < 4; ++reg) {
            const int grow = row0 + rt * 16 + (l >> 4) * 4 + reg;
            const size_t off = (size_t)grow * H + col;
            const float ig = fsigmoid(acc[0][reg] + bi);
            const float fg = fsigmoid(acc[1][reg] + bf);
            const float gg = ftanh(acc[2][reg] + bg);
            const float og = fsigmoid(acc[3][reg] + bo);
            const float c2 = fmaf(fg, c[off], ig * gg);
            c[off] = c2;
            h[off] = (f16)(og * ftanh(c2));
        }
    }
}

// ---------------- gather + embed fused ----------------
// Per block: TR=64 node rows. Phase 1: stage ht (K cols 0..63) and CSR-gather
// agg (K cols 64..127) directly into swizzled LDS. Phase 2: MFMA embed.
// Also writes the n_enc encoder half of xnode.
__global__ __launch_bounds__(256) void gather_embed(
    const float* __restrict__ xn,
    const f16* __restrict__ ht, const f16* __restrict__ hs,
    const int* __restrict__ ptr, const int* __restrict__ rowidx,
    const float* __restrict__ n_enc_w, const float* __restrict__ n_enc_b,
    const f16* __restrict__ Wt_ee,   // [64][128]
    const float* __restrict__ ee_b,
    f16* __restrict__ xnode)
{
    constexpr int TR = 64;
    __shared__ char Xls[TR * 256];
    const int row0 = blockIdx.x * TR;
    const int t = threadIdx.x;
    const int wv = t >> 6, l = t & 63;
    const int lane15 = l & 15, kgrp = l >> 4;

    // B fragments resident (wave wv owns cols 16wv..16wv+16 of the 64)
    const int col = wv * 16 + lane15;
    f16x8 bfrag[4];
    {
        const f16* bp = Wt_ee + (size_t)col * 128 + kgrp * 8;
        #pragma unroll
        for (int ks = 0; ks < 4; ++ks) bfrag[ks] = ld_frag16(bp + ks * 32);
    }

    // stage ht -> K cols 0..63
    for (int i = t; i < TR * 16; i += 256) {
        const int r = i / 16, j4 = (i % 16) * 4;
        const uint2 v = *(const uint2*)&ht[(size_t)(row0 + r) * 64 + j4];
        const int byte = r * 256 + ((j4 * 2) ^ ((r & 7) << 4));
        *(uint2*)(Xls + byte) = v;
    }

    // CSR gather -> K cols 64..127 (4 threads per row, 16 f16 cols each)
    {
        const int r = t >> 2, q = t & 3;     // row, col-quarter
        const int n = row0 + r;
        const int beg = ptr[n], end = ptr[n + 1];
        const unsigned int* hs32 = (const unsigned int*)hs;
        float acc[16];
        #pragma unroll
        for (int j = 0; j < 16; ++j) acc[j] = 0.f;
        for (int i = beg; i < end; ++i) {
            const int e = rowidx[i];
            const unsigned int* ep = hs32 + (size_t)e * 32 + q * 8;
            #pragma unroll
            for (int j = 0; j < 8; ++j) {
                union { unsigned int u; f16 h[2]; } v;
                v.u = ep[j];
                acc[2 * j]     += (float)v.h[0];
                acc[2 * j + 1] += (float)v.h[1];
            }
        }
        #pragma unroll
        for (int j = 0; j < 8; ++j) {
            const int byte = r * 256 + ((128 + q * 32 + j * 4) ^ ((r & 7) << 4));
            *(unsigned int*)(Xls + byte) = pk2(acc[2 * j], acc[2 * j + 1]);
        }
    }
    __syncthreads();

    const float bb = ee_b[col];
    #pragma unroll
    for (int rt = 0; rt < TR / 16; ++rt) {
        const int arow = rt * 16 + lane15;
        const char* abase = Xls + arow * 256;
        f16x8 afrag[4];
        #pragma unroll
        for (int ks = 0; ks < 4; ++ks) {
            const int byte = (ks * 64 + kgrp * 16) ^ ((arow & 7) << 4);
            afrag[ks] = ld_frag16(abase + byte);
        }
        f32x4 acc;
        #pragma unroll
        for (int r = 0; r < 4; ++r) acc[r] = 0.f;
        #pragma unroll
        for (int ks = 0; ks < 4; ++ks)
            acc = __builtin_amdgcn_mfma_f32_16x16x32_f16(afrag[ks], bfrag[ks], acc, 0, 0, 0);
        #pragma unroll
        for (int reg = 0; reg < 4; ++reg) {
            const int grow = row0 + rt * 16 + (l >> 4) * 4 + reg;
            xnode[(size_t)grow * 128 + 64 + col] = (f16)fmaxf(0.f, acc[reg] + bb);
        }
    }

    // encoder half: cols 0..63
    for (int i = t; i < TR * 32; i += 256) {
        const int r = i >> 5, j2 = (i & 31) * 2;
        const int grow = row0 + r;
        const float x = xn[grow];
        const float e0 = fmaxf(0.f, fmaf(x, n_enc_w[j2],     n_enc_b[j2]));
        const float e1 = fmaxf(0.f, fmaf(x, n_enc_w[j2 + 1], n_enc_b[j2 + 1]));
        *(unsigned int*)&xnode[(size_t)grow * 128 + j2] = pk2(e0, e1);
    }
}

// ---------------- node LSTM (H=128), B-resident, 8 waves ----------------
__global__ __launch_bounds__(512) void node_lstm(
    const f16* __restrict__ xin,
    const f16* __restrict__ Wt,     // [512][256]
    const float* __restrict__ bias, // [512]
    f16* __restrict__ h, float* __restrict__ c)
{
    constexpr int H = 128, K = 256, KSTEPS = 8, ROWB = 512, TR = 128;
    __shared__ char Xls[TR * ROWB];

    const int row0 = blockIdx.x * TR;
    const int t = threadIdx.x;
    const int wv = t >> 6, l = t & 63;
    const int lane15 = l & 15, kgrp = l >> 4;

    f16x8 bfrag[4][KSTEPS];
    #pragma unroll
    for (int q = 0; q < 4; ++q) {
        const int col = q * H + wv * 16 + lane15;
        const f16* bp = Wt + (size_t)col * K + kgrp * 8;
        #pragma unroll
        for (int ks = 0; ks < KSTEPS; ++ks)
            bfrag[q][ks] = ld_frag16(bp + ks * 32);
    }

    for (int i = t; i < TR * (H / 4); i += 512) {
        const int r = i / (H / 4), j4 = (i % (H / 4)) * 4;
        const uint2 v = *(const uint2*)&xin[(size_t)(row0 + r) * H + j4];
        const int byte = r * ROWB + ((j4 * 2) ^ ((r & 7) << 4));
        *(uint2*)(Xls + byte) = v;
    }
    for (int i = t; i < TR * (H / 4); i += 512) {
        const int r = i / (H / 4), j4 = (i % (H / 4)) * 4;
        const uint2 v = *(const uint2*)&h[(size_t)(row0 + r) * H + j4];
        const int byte = r * ROWB + ((H * 2 + j4 * 2) ^ ((r & 7) << 4));
        *(uint2*)(Xls + byte) = v;
    }
    __syncthreads();

    const int col = wv * 16 + lane15;
    const float bi = bias[0 * H + col];
    const float bf = bias[1 * H + col];
    const float bg = bias[2 * H + col];
    const float bo = bias[3 * H + col];

    #pragma unroll 2
    for (int rt = 0; rt < TR / 16; ++rt) {
        const int arow = rt * 16 + lane15;
        const char* abase = Xls + arow * ROWB;
        f16x8 afrag[KSTEPS];
        #pragma unroll
        for (int ks = 0; ks < KSTEPS; ++ks) {
            const int byte = (ks * 64 + kgrp * 16) ^ ((arow & 7) << 4);
            afrag[ks] = ld_frag16(abase + byte);
        }
        f32x4 acc[4];
        #pragma unroll
        for (int q = 0; q < 4; ++q)
            #pragma unroll
            for (int r = 0; r < 4; ++r) acc[q][r] = 0.f;
        #pragma unroll
        for (int ks = 0; ks < KSTEPS; ++ks)
            #pragma unroll
            for (int q = 0; q < 4; ++q)
                acc[q] = __builtin_amdgcn_mfma_f32_16x16x32_f16(
                    afrag[ks], bfrag[q][ks], acc[q], 0, 0, 0);
        #pragma unroll
        for (int reg = 0; reg < 4; ++reg) {
            const int grow = row0 + rt * 16 + (l >> 4) * 4 + reg;
            const size_t off = (size_t)grow * H + col;
            const float ig = fsigmoid(acc[0][reg] + bi);
            const float fg = fsigmoid(acc[1][reg] + bf);
            const float gg = ftanh(acc[2][reg] + bg);
            const float og = fsigmoid(acc[3][reg] + bo);
            const float c2 = fmaf(fg, c[off], ig * gg);
            c[off] = c2;
            h[off] = (f16)(og * ftanh(c2));
        }
    }
}

// ---------------- CSR build (once; inc is step-invariant) ----------------
__global__ __launch_bounds__(256) void count_kernel(
    const int* __restrict__ inc, int* __restrict__ cnt)
{
    const int slot = blockIdx.x * 256 + threadIdx.x;
    atomicAdd(&cnt[inc[slot]], 1);
}

__global__ __launch_bounds__(1024) void scan_kernel(
    const int* __restrict__ cnt, int* __restrict__ ptr)
{
    __shared__ int sums[1024];
    const int t = threadIdx.x;
    const int base = t * 32;
    int local[32];
    int s = 0;
    #pragma unroll
    for (int i = 0; i < 32; ++i) { local[i] = s; s += cnt[base + i]; }
    sums[t] = s;
    __syncthreads();
    for (int off = 1; off < 1024; off <<= 1) {
        int v = 0;
        if (t >= off) v = sums[t - off];
        __syncthreads();
        sums[t] += v;
        __syncthreads();
    }
    const int excl = sums[t] - s;
    #pragma unroll
    for (int i = 0; i < 32; ++i) ptr[base + i] = excl + local[i];
    if (t == 1023) ptr[NN] = sums[1023];
}

__global__ __launch_bounds__(256) void fill_kernel(
    const int* __restrict__ inc, const int* __restrict__ ptr,
    int* __restrict__ cur, int* __restrict__ rowidx)
{
    const int slot = blockIdx.x * 256 + threadIdx.x;
    const int n = inc[slot];
    const int pos = atomicAdd(&cur[n], 1);
    rowidx[ptr[n] + pos] = slot >> 1;
}

// ---------------- output projection: one row per thread ----------------
__global__ __launch_bounds__(256) void out_kernel(
    const f16* __restrict__ hn, const float* __restrict__ out_w,
    const float* __restrict__ out_b, float* __restrict__ out)
{
    __shared__ float wls[128];
    if (threadIdx.x < 128) wls[threadIdx.x] = out_w[threadIdx.x];
    __syncthreads();
    const int r = blockIdx.x * 256 + threadIdx.x;
    const uint4* hp = (const uint4*)(hn + (size_t)r * 128);
    float p = 0.f;
    #pragma unroll
    for (int k4 = 0; k4 < 8; ++k4) {
        const uint4 v = hp[k4];
        const unsigned int u[4] = { v.x, v.y, v.z, v.w };
        #pragma unroll
        for (int j = 0; j < 4; ++j) {
            union { unsigned int w; f16 h[2]; } x;
            x.w = u[j];
            p = fmaf((float)x.h[0], wls[k4 * 16 + j * 4],     p);  // placeholder idx fixed below
            p = fmaf((float)x.h[1], wls[k4 * 16 + j * 4 + 1], p);
        }
    }
    out[r] = p + out_b[0];
}

// NOTE: out_kernel above uses wls[k4*16 + j*4(+1)] which would be wrong;
// correct contiguous indexing implemented here and used instead.
__global__ __launch_bounds__(256) void out_kernel2(
    const f16* __restrict__ hn, const float* __restrict__ out_w,
    const float* __restrict__ out_b, float* __restrict__ out)
{
    __shared__ float wls[128];
    if (threadIdx.x < 128) wls[threadIdx.x] = out_w[threadIdx.x];
    __syncthreads();
    const int r = blockIdx.x * 256 + threadIdx.x;
    const unsigned int* hp = (const unsigned int*)(hn + (size_t)r * 128);
    float p = 0.f;
    #pragma unroll
    for (int k = 0; k < 64; ++k) {
        union { unsigned int w; f16 h[2]; } x;
        x.w = hp[k];
        p = fmaf((float)x.h[0], wls[2 * k],     p);
        p = fmaf((float)x.h[1], wls[2 * k + 1], p);
    }
    out[r] = p + out_b[0];
}

// ---------------- weight transpose+convert (once) ----------------
__global__ __launch_bounds__(256) void transpose_w_kernel(
    const float* __restrict__ Wih, const float* __restrict__ Whh,
    f16* __restrict__ dst, int Hk, int K, int fourH)
{
    const int tid = blockIdx.x * 256 + threadIdx.x;
    if (tid >= K * fourH) return;
    const int col = tid / K, k = tid % K;
    const float v = (k < Hk) ? Wih[(size_t)k * fourH + col]
                             : Whh[(size_t)(k - Hk) * fourH + col];
    dst[tid] = (f16)v;
}

__global__ __launch_bounds__(256) void cvt_kernel(
    const float* __restrict__ src, f16* __restrict__ dst, int n2)
{
    const int i = blockIdx.x * 256 + threadIdx.x;
    if (i >= n2) return;
    const float2 v = ((const float2*)src)[i];
    ((unsigned int*)dst)[i] = pk2(v.x, v.y);
}

extern "C" void kernel_launch(void* const* d_in, const int* in_sizes, int n_in,
                              void* d_out, int out_size, void* d_ws, size_t ws_size,
                              hipStream_t stream) {
    const float* data_nodes = (const float*)d_in[0];
    const float* data_tE    = (const float*)d_in[1];
    const float* data_sE    = (const float*)d_in[2];
    const float* h_n0 = (const float*)d_in[3];
    const float* c_n0 = (const float*)d_in[4];
    const float* h_t0 = (const float*)d_in[5];
    const float* c_t0 = (const float*)d_in[6];
    const float* h_s0 = (const float*)d_in[7];
    const float* c_s0 = (const float*)d_in[8];
    const int*   inc  = (const int*)d_in[9];
    const float* t_enc_w = (const float*)d_in[10];
    const float* t_enc_b = (const float*)d_in[11];
    const float* t_Wih   = (const float*)d_in[12];
    const float* t_Whh   = (const float*)d_in[13];
    const float* t_b     = (const float*)d_in[14];
    const float* s_enc_w = (const float*)d_in[15];
    const float* s_enc_b = (const float*)d_in[16];
    const float* s_Wih   = (const float*)d_in[17];
    const float* s_Whh   = (const float*)d_in[18];
    const float* s_b     = (const float*)d_in[19];
    const float* n_enc_w = (const float*)d_in[20];
    const float* n_enc_b = (const float*)d_in[21];
    const float* ee_w    = (const float*)d_in[22];
    const float* ee_b    = (const float*)d_in[23];
    const float* n_Wih   = (const float*)d_in[24];
    const float* n_Whh   = (const float*)d_in[25];
    const float* n_b     = (const float*)d_in[26];
    const float* out_w   = (const float*)d_in[27];
    const float* out_b   = (const float*)d_in[28];
    float* out = (float*)d_out;

    // ---- workspace layout ----
    char* p = (char*)d_ws;
    f16*  ht16    = (f16*)p;  p += (size_t)NN * 64 * 2;
    f16*  hs16    = (f16*)p;  p += (size_t)EE * 64 * 2;
    f16*  hn16    = (f16*)p;  p += (size_t)NN * 128 * 2;
    f16*  xnode16 = (f16*)p;  p += (size_t)NN * 128 * 2;
    float* ct     = (float*)p; p += (size_t)NN * 64 * 4;
    float* cs     = (float*)p; p += (size_t)EE * 64 * 4;
    float* cn     = (float*)p; p += (size_t)NN * 128 * 4;
    f16*  Wt_t    = (f16*)p;  p += (size_t)256 * 128 * 2;
    f16*  Wt_s    = (f16*)p;  p += (size_t)256 * 128 * 2;
    f16*  Wt_n    = (f16*)p;  p += (size_t)512 * 256 * 2;
    f16*  Wt_ee   = (f16*)p;  p += (size_t)64 * 128 * 2;
    int*  csr_ptr = (int*)p;  p += (size_t)(NN + 8) * 4;
    int*  csr_row = (int*)p;  p += (size_t)2 * EE * 4;
    int*  cnt     = (int*)p;  p += (size_t)NN * 4;
    int*  cur     = (int*)p;  p += (size_t)NN * 4;

    // ---- one-time: state init, weight conversion, CSR ----
    cvt_kernel<<<(NN * 64 / 2 + 255) / 256, 256, 0, stream>>>(h_t0, ht16, NN * 64 / 2);
    cvt_kernel<<<(EE * 64 / 2 + 255) / 256, 256, 0, stream>>>(h_s0, hs16, EE * 64 / 2);
    cvt_kernel<<<(NN * 128 / 2 + 255) / 256, 256, 0, stream>>>(h_n0, hn16, NN * 128 / 2);
    hipMemcpyAsync(ct, c_t0, (size_t)NN * 64 * 4, hipMemcpyDeviceToDevice, stream);
    hipMemcpyAsync(cs, c_s0, (size_t)EE * 64 * 4, hipMemcpyDeviceToDevice, stream);
    hipMemcpyAsync(cn, c_n0, (size_t)NN * 128 * 4, hipMemcpyDeviceToDevice, stream);

    transpose_w_kernel<<<(256 * 128 + 255) / 256, 256, 0, stream>>>(t_Wih, t_Whh, Wt_t, 64, 128, 256);
    transpose_w_kernel<<<(256 * 128 + 255) / 256, 256, 0, stream>>>(s_Wih, s_Whh, Wt_s, 64, 128, 256);
    transpose_w_kernel<<<(512 * 256 + 255) / 256, 256, 0, stream>>>(n_Wih, n_Whh, Wt_n, 128, 256, 512);
    transpose_w_kernel<<<(64 * 128 + 255) / 256, 256, 0, stream>>>(ee_w, ee_w, Wt_ee, 128, 128, 64);

    hipMemsetAsync(cnt, 0, NN * sizeof(int), stream);
    hipMemsetAsync(cur, 0, NN * sizeof(int), stream);
    count_kernel<<<(2 * EE) / 256, 256, 0, stream>>>(inc, cnt);
    scan_kernel<<<1, 1024, 0, stream>>>(cnt, csr_ptr);
    fill_kernel<<<(2 * EE) / 256, 256, 0, stream>>>(inc, csr_ptr, cur, csr_row);

    const int edgeGrid = NN / 64 + EE / 64;   // 512 + 2048

    for (int st = 0; st < S_LEN; ++st) {
        const float* xt = data_tE + (size_t)st * NN * 2;
        const float* xs = data_sE + (size_t)st * EE * 2;
        const float* xn = data_nodes + (size_t)st * NN;

        edge_lstm_fused<<<edgeGrid, 256, 0, stream>>>(
            xt, xs, t_enc_w, t_enc_b, s_enc_w, s_enc_b,
            Wt_t, Wt_s, t_b, s_b, ht16, ct, hs16, cs);
        gather_embed<<<NN / 64, 256, 0, stream>>>(
            xn, ht16, hs16, csr_ptr, csr_row,
            n_enc_w, n_enc_b, Wt_ee, ee_b, xnode16);
        node_lstm<<<NN / 128, 512, 0, stream>>>(
            xnode16, Wt_n, n_b, hn16, cn);
        out_kernel2<<<NN / 256, 256, 0, stream>>>(
            hn16, out_w, out_b, out + (size_t)st * NN);
    }
}